// Round 12
// baseline (27.265 us; speedup 1.0000x reference)
//
#include <hip/hip_runtime.h>
#include <math.h>

#define NVOX 16384
#define NRAYS 2048
#define CAP 256             // per-ray hit capacity (expected ~15-40 hits)
#define BLK 1024
#define RPB 4               // rays per block; phase 2 uses one wave per ray
#define STOPT 0.01f
#define FARP 100.0f

// Single-node flat rasterizer.
// Centered slab test: tc = fma(p,iv,of); tn_ax = fma(-s,ai2,tc); tf_ax = fma(s,ai2,tc)
// with ai2 = 0.5*|iv|. Hit iff tf > max(tn,0) (== reference tf>tn && tf>0).
// Branches coalesced: one outer branch per voxel over the OR of 4 ray masks.
__global__ __launch_bounds__(BLK, 4) void raster_flat_kernel(
    const float* __restrict__ pos,   // (NVOX,3)
    const float* __restrict__ siz,   // (NVOX,)
    const float* __restrict__ den,   // (NVOX,)
    const float* __restrict__ col,   // (NVOX,3)
    const float* __restrict__ rob,   // (NRAYS,3)
    const float* __restrict__ rdb,   // (NRAYS,3)
    float* __restrict__ out)         // rgb[NRAYS*3] | depth[NRAYS] | weights[NRAYS]
{
    __shared__ float s_key[RPB][CAP];
    __shared__ float s_op [RPB][CAP];
    __shared__ int   s_cid[RPB][CAP];
    __shared__ int   s_cnt[RPB];

    const int tid  = threadIdx.x;
    const int ray0 = blockIdx.x * RPB;
    if (tid < RPB) s_cnt[tid] = 0;
    __syncthreads();

    // per-ray constants (block-uniform addresses -> scalar loads)
    float ivx[RPB], ivy[RPB], ivz[RPB];      // 1/d
    float aix[RPB], aiy[RPB], aiz[RPB];      // 0.5*|1/d|
    float ofx[RPB], ofy[RPB], ofz[RPB];      // -o/d
#pragma unroll
    for (int r = 0; r < RPB; ++r) {
        const int ray = ray0 + r;
        const float ox = rob[ray*3], oy = rob[ray*3+1], oz = rob[ray*3+2];
        const float dx = rdb[ray*3], dy = rdb[ray*3+1], dz = rdb[ray*3+2];
        ivx[r] = 1.0f/dx;      ivy[r] = 1.0f/dy;      ivz[r] = 1.0f/dz;
        aix[r] = 0.5f*fabsf(ivx[r]); aiy[r] = 0.5f*fabsf(ivy[r]); aiz[r] = 0.5f*fabsf(ivz[r]);
        ofx[r] = -ox*ivx[r];   ofy[r] = -oy*ivy[r];   ofz[r] = -oz*ivz[r];
    }

    const float4* __restrict__ pos4 = (const float4*)pos;   // 12288 float4s
    const float4* __restrict__ siz4 = (const float4*)siz;   // 4096 float4s

    // Phase 1: slab-test every voxel against RPB rays; push hits to LDS.
#pragma unroll
    for (int k = 0; k < NVOX / (BLK * 4); ++k) {
        const int g  = tid + k * BLK;        // float4-group index
        const float4 p0 = pos4[3*g + 0];
        const float4 p1 = pos4[3*g + 1];
        const float4 p2 = pos4[3*g + 2];
        const float4 s  = siz4[g];
        const int v0 = 4 * g;

        float vx[4], vy[4], vz[4], vs[4];
        vx[0] = p0.x; vy[0] = p0.y; vz[0] = p0.z; vs[0] = s.x;
        vx[1] = p0.w; vy[1] = p1.x; vz[1] = p1.y; vs[1] = s.y;
        vx[2] = p1.z; vy[2] = p1.w; vz[2] = p2.x; vs[2] = s.z;
        vx[3] = p2.y; vy[3] = p2.z; vz[3] = p2.w; vs[3] = s.w;

#pragma unroll
        for (int q = 0; q < 4; ++q) {
            const float sz = vs[q];
            const float px = vx[q], py = vy[q], pz = vz[q];
            float tns[RPB], tfs[RPB];
            bool  hit[RPB];
#pragma unroll
            for (int r = 0; r < RPB; ++r) {
                const float tcx = fmaf(px, ivx[r], ofx[r]);
                const float tcy = fmaf(py, ivy[r], ofy[r]);
                const float tcz = fmaf(pz, ivz[r], ofz[r]);
                const float tnx = fmaf(-sz, aix[r], tcx);
                const float tny = fmaf(-sz, aiy[r], tcy);
                const float tnz = fmaf(-sz, aiz[r], tcz);
                const float tfx = fmaf( sz, aix[r], tcx);
                const float tfy = fmaf( sz, aiy[r], tcy);
                const float tfz = fmaf( sz, aiz[r], tcz);
                const float tn = fmaxf(fmaxf(tnx, tny), tnz);   // v_max3
                const float tf = fminf(fminf(tfx, tfy), tfz);   // v_min3
                tns[r] = tn; tfs[r] = tf;
                hit[r] = (tf > fmaxf(tn, 0.0f));
            }
            // one outer branch per voxel (P(skip) ~ 79%) instead of 4 rare branches
            if (hit[0] || hit[1] || hit[2] || hit[3]) {
                const int v = v0 + q;
                const float ed = expf(den[v]);     // shared across rays hitting this voxel
#pragma unroll
                for (int r = 0; r < RPB; ++r) {
                    if (hit[r]) {
                        const float op = 1.0f - expf(-ed * (tfs[r] - tns[r]) * (1.0f/7.0f));
                        const int kk = atomicAdd(&s_cnt[r], 1);
                        if (kk < CAP) { s_key[r][kk] = tns[r]; s_op[r][kk] = op; s_cid[r][kk] = v; }
                    }
                }
            }
        }
    }
    __syncthreads();

    // Phase 2: wave wv composites ray ray0+wv via O(n^2) exclusive product
    // (reference semantics: w_i = T_excl_i*op_i if T_excl_i >= STOP_T, order-free)
    const int wv = tid >> 6, lane = tid & 63;
    if (wv < RPB) {
        const int n = min(s_cnt[wv], CAP);
        float ar = 0.f, ag = 0.f, ab = 0.f, ad = 0.f, aw = 0.f;
        for (int i = lane; i < n; i += 64) {
            const float ti = s_key[wv][i], oi = s_op[wv][i];
            float T = 1.0f;
            for (int j = 0; j < n; ++j)
                T *= (s_key[wv][j] < ti) ? (1.0f - s_op[wv][j]) : 1.0f;   // LDS broadcast
            const float w = (T >= STOPT) ? T * oi : 0.0f;
            const int c = s_cid[wv][i];
            ar += w * col[c*3+0];
            ag += w * col[c*3+1];
            ab += w * col[c*3+2];
            ad += w * ti;
            aw += w;
        }
#pragma unroll
        for (int off = 32; off > 0; off >>= 1) {
            ar += __shfl_down(ar, off);
            ag += __shfl_down(ag, off);
            ab += __shfl_down(ab, off);
            ad += __shfl_down(ad, off);
            aw += __shfl_down(aw, off);
        }
        if (lane == 0) {
            const int ray = ray0 + wv;
            out[ray*3+0] = ar;
            out[ray*3+1] = ag;
            out[ray*3+2] = ab;
            out[NRAYS*3 + ray] = (n > 0) ? ad : FARP;
            out[NRAYS*4 + ray] = aw;
        }
    }
}

extern "C" void kernel_launch(void* const* d_in, const int* in_sizes, int n_in,
                              void* d_out, int out_size, void* d_ws, size_t ws_size,
                              hipStream_t stream) {
    const float* pos = (const float*)d_in[0];
    const float* siz = (const float*)d_in[1];
    const float* den = (const float*)d_in[2];
    const float* col = (const float*)d_in[3];
    const float* rob = (const float*)d_in[4];
    const float* rdb = (const float*)d_in[5];
    float* out = (float*)d_out;

    raster_flat_kernel<<<NRAYS / RPB, BLK, 0, stream>>>(pos, siz, den, col, rob, rdb, out);
}